// Round 1
// baseline (24.859 us; speedup 1.0000x reference)
//
#include <hip/hip_runtime.h>

// ReservoirEmbedding: out[b,s,:] = sum_r w_eff[reservoir_lookup[base_indices[b,s], r], :]
// with w_eff row FROZEN_INDEX (=0) zeroed.
// Shapes: base_indices [16,2048] i32, reservoir_lookup [50257,8] i32,
//         embedding_weight [50257,128] f32, out [16,2048,128] f32.

#define VOCAB 50257
#define FEATURES 128
#define RESERVOIR 8
#define FROZEN_INDEX 0
#define NTOK (16 * 2048)

__global__ __launch_bounds__(256) void reservoir_embed_kernel(
    const int* __restrict__ base_indices,      // [NTOK]
    const int* __restrict__ reservoir_lookup,  // [VOCAB][RESERVOIR]
    const float* __restrict__ weight,          // [VOCAB][FEATURES]
    float* __restrict__ out)                   // [NTOK][FEATURES]
{
    const int gid  = blockIdx.x * blockDim.x + threadIdx.x;
    const int tok  = gid >> 5;        // 32 lanes per token
    const int lane = gid & 31;        // lane owns float4 chunk: features [4*lane, 4*lane+4)
    if (tok >= NTOK) return;

    const int base = base_indices[tok];
    const int* rlp = reservoir_lookup + (long long)base * RESERVOIR;

    // Load all 8 indices first (same addr across the 32-lane group -> broadcast hits).
    int idx[RESERVOIR];
#pragma unroll
    for (int r = 0; r < RESERVOIR; ++r) idx[r] = rlp[r];

    // Issue all 8 gathered float4 loads up front for MLP; mask frozen row by multiply.
    float4 rows[RESERVOIR];
#pragma unroll
    for (int r = 0; r < RESERVOIR; ++r) {
        const float4* p = reinterpret_cast<const float4*>(
            weight + (long long)idx[r] * FEATURES + lane * 4);
        rows[r] = *p;
    }

    float4 acc = make_float4(0.f, 0.f, 0.f, 0.f);
#pragma unroll
    for (int r = 0; r < RESERVOIR; ++r) {
        const float m = (idx[r] != FROZEN_INDEX) ? 1.0f : 0.0f;
        acc.x += m * rows[r].x;
        acc.y += m * rows[r].y;
        acc.z += m * rows[r].z;
        acc.w += m * rows[r].w;
    }

    *reinterpret_cast<float4*>(out + (long long)tok * FEATURES + lane * 4) = acc;
}

extern "C" void kernel_launch(void* const* d_in, const int* in_sizes, int n_in,
                              void* d_out, int out_size, void* d_ws, size_t ws_size,
                              hipStream_t stream) {
    const int*   base_indices     = (const int*)d_in[0];
    const int*   reservoir_lookup = (const int*)d_in[1];
    const float* weight           = (const float*)d_in[2];
    float*       out              = (float*)d_out;

    const int threads = 256;                 // 8 tokens per block
    const int total   = NTOK * 32;           // 32 lanes per token
    const int blocks  = (total + threads - 1) / threads;
    reservoir_embed_kernel<<<blocks, threads, 0, stream>>>(
        base_indices, reservoir_lookup, weight, out);
}